// Round 10
// baseline (582.909 us; speedup 1.0000x reference)
//
#include <hip/hip_runtime.h>
#include <math.h>

#define B_  2
#define L_  2000
#define DM_ 256
#define DI_ 512
#define DS_ 16
#define NL_ 4
#define BL_ (B_*L_)     // 4000
#define BLP_ 4096       // rows padded to multiple of 64
#define NC_ 50          // scan chunks
#define CL_ 40          // chunk length (L_ = NC_*CL_)

typedef unsigned short ushort_t;
typedef __attribute__((ext_vector_type(8))) short bf16x8;
typedef __attribute__((ext_vector_type(4))) float f32x4;

__device__ __forceinline__ float siluf(float x) {
    return x / (1.f + __expf(-x));
}

__device__ __forceinline__ ushort_t f2bf(float x) {
    unsigned int u = __float_as_uint(x);
    unsigned int r = (u + 0x7FFFu + ((u >> 16) & 1u)) >> 16;
    return (ushort_t)r;
}

__device__ __forceinline__ float bf2f(ushort_t v) {
    return __uint_as_float(((unsigned int)v) << 16);
}

// ---------------- fp32 -> bf16 conversion, 3 segments in one launch ----------------
__global__ __launch_bounds__(256) void f2bf3_kernel(
    const float* __restrict__ s0, const float* __restrict__ s1,
    const float* __restrict__ s2, ushort_t* __restrict__ d0,
    ushort_t* __restrict__ d1, ushort_t* __restrict__ d2,
    int N0, int N1, int N2)
{
    int i = blockIdx.x*256 + threadIdx.x;
    const float* s; ushort_t* d; int j;
    if (i < N0)           { s = s0; d = d0; j = i; }
    else if (i < N0+N1)   { s = s1; d = d1; j = i - N0; }
    else if (i < N0+N1+N2){ s = s2; d = d2; j = i - N0 - N1; }
    else return;
    float4 v = *(const float4*)(s + 4*j);
    ushort_t o[4] = {f2bf(v.x), f2bf(v.y), f2bf(v.z), f2bf(v.w)};
    *(ushort2*)(d + 4*j)     = *(ushort2*)&o[0];
    *(ushort2*)(d + 4*j + 2) = *(ushort2*)&o[2];
}

// ---------------- embed: h = x*biw + bib + gene_emb + mod_emb ----------------
__global__ __launch_bounds__(256) void embed_kernel(
    const float* __restrict__ x, const float* __restrict__ biw,
    const float* __restrict__ bib, const float* __restrict__ ge,
    const float* __restrict__ me, float* __restrict__ h)
{
    int bl = blockIdx.x, d = threadIdx.x;
    int l = bl % L_;
    h[(size_t)bl*DM_ + d] = x[bl]*biw[d] + bib[d] + ge[(size_t)l*DM_ + d] + me[d];
}

// ---------------- layernorm over D_MODEL=256 -> bf16 output ----------------
__global__ __launch_bounds__(256) void ln_kernel(
    const float* __restrict__ h, const float* __restrict__ w,
    const float* __restrict__ b, ushort_t* __restrict__ out)
{
    __shared__ float sm[4];
    int row = blockIdx.x, tid = threadIdx.x;
    float v = h[(size_t)row*DM_ + tid];
    float s = v;
    #pragma unroll
    for (int o = 32; o > 0; o >>= 1) s += __shfl_down(s, o);
    if ((tid & 63) == 0) sm[tid >> 6] = s;
    __syncthreads();
    float mu = (sm[0]+sm[1]+sm[2]+sm[3]) * (1.f/DM_);
    __syncthreads();
    float d = v - mu;
    float q = d*d;
    #pragma unroll
    for (int o = 32; o > 0; o >>= 1) q += __shfl_down(q, o);
    if ((tid & 63) == 0) sm[tid >> 6] = q;
    __syncthreads();
    float var = (sm[0]+sm[1]+sm[2]+sm[3]) * (1.f/DM_);
    out[(size_t)row*DM_ + tid] = f2bf(d * rsqrtf(var + 1e-5f) * w[tid] + b[tid]);
}

// ---------------- bf16 MFMA GEMM: C[m,n] (+)= sum_k A[m,k]*W[n,k] ----------------
// OutT = float (ACCUM +=) or ushort_t (bf16 store).
template<bool ACCUM, typename OutT>
__global__ __launch_bounds__(256) void gemm_mfma(
    const ushort_t* __restrict__ A, const ushort_t* __restrict__ W,
    OutT* __restrict__ C, int ldc, int K)
{
    __shared__ ushort_t a_s[128*64];
    __shared__ ushort_t b_s[128*64];
    const int r0 = blockIdx.x*128, c0 = blockIdx.y*128;
    const int tid = threadIdx.x;
    const int lane = tid & 63, w = tid >> 6;
    const int wm = (w & 1)*64, wn = (w >> 1)*64;
    const int qd = lane >> 4, l16 = lane & 15;
    f32x4 acc[4][4] = {};
    for (int kc = 0; kc < K; kc += 64) {
        #pragma unroll
        for (int q = 0; q < 4; q++) {
            int ch = tid + 256*q;              // 0..1023
            int row = ch >> 3, col8 = (ch & 7)*8;
            *(bf16x8*)&a_s[row*64 + col8] =
                *(const bf16x8*)(A + (size_t)(r0 + row)*K + kc + col8);
            *(bf16x8*)&b_s[row*64 + col8] =
                *(const bf16x8*)(W + (size_t)(c0 + row)*K + kc + col8);
        }
        __syncthreads();
        #pragma unroll
        for (int ks = 0; ks < 2; ks++) {
            bf16x8 af[4], bf[4];
            #pragma unroll
            for (int i = 0; i < 4; i++)
                af[i] = *(const bf16x8*)&a_s[(wm + i*16 + l16)*64 + ks*32 + qd*8];
            #pragma unroll
            for (int j = 0; j < 4; j++)
                bf[j] = *(const bf16x8*)&b_s[(wn + j*16 + l16)*64 + ks*32 + qd*8];
            #pragma unroll
            for (int i = 0; i < 4; i++) {
                #pragma unroll
                for (int j = 0; j < 4; j++)
                    acc[i][j] = __builtin_amdgcn_mfma_f32_16x16x32_bf16(
                        af[i], bf[j], acc[i][j], 0, 0, 0);
            }
        }
        __syncthreads();
    }
    // C/D layout: col = lane&15, row = (lane>>4)*4 + reg
    #pragma unroll
    for (int i = 0; i < 4; i++) {
        #pragma unroll
        for (int j = 0; j < 4; j++) {
            #pragma unroll
            for (int r = 0; r < 4; r++) {
                int row = r0 + wm + i*16 + qd*4 + r;
                int col = c0 + wn + j*16 + l16;
                size_t idx = (size_t)row*ldc + col;
                if constexpr (ACCUM)                  C[idx] += acc[i][j][r];
                else if constexpr (sizeof(OutT) == 2) C[idx]  = f2bf(acc[i][j][r]);
                else                                  C[idx]  = acc[i][j][r];
            }
        }
    }
}

// ---------------- conv(4) + silu on bf16 xz; writes u_bf (b,l,c) bf16 ----------------
__global__ __launch_bounds__(256) void conv_silu_kernel(
    const ushort_t* __restrict__ xz, const float* __restrict__ cw,
    const float* __restrict__ cb, ushort_t* __restrict__ u_bf)
{
    __shared__ ushort_t xs[67][72];
    __shared__ ushort_t us[64][72];
    const int l0 = blockIdx.x * 64, c0 = blockIdx.y * 64, b = blockIdx.z;
    const int tid = threadIdx.x;
    // stage xz tile rows l0-3 .. l0+63 (64 c each, bf16)
    for (int f = tid; f < 67*8; f += 256) {
        int row = f >> 3, c8 = (f & 7) * 8;
        int l = l0 - 3 + row;
        uint4 v = {0u, 0u, 0u, 0u};
        if (l >= 0 && l < L_)
            v = *(const uint4*)(xz + (size_t)(b*L_ + l)*1024 + c0 + c8);
        *(uint4*)&xs[row][c8] = v;
    }
    __syncthreads();
    // conv: thread -> fixed c, 16 consecutive l
    const int c_loc = tid & 63, lq = tid >> 6;
    const int c = c0 + c_loc;
    float4 wv = *(const float4*)(cw + c*4);
    float bias = cb[c];
    float x0 = bf2f(xs[lq*16 + 0][c_loc]);
    float x1 = bf2f(xs[lq*16 + 1][c_loc]);
    float x2 = bf2f(xs[lq*16 + 2][c_loc]);
    #pragma unroll
    for (int j = 0; j < 16; j++) {
        float x3 = bf2f(xs[lq*16 + 3 + j][c_loc]);
        float v = fmaf(x0, wv.x, fmaf(x1, wv.y, fmaf(x2, wv.z, fmaf(x3, wv.w, bias))));
        us[lq*16 + j][c_loc] = f2bf(siluf(v));
        x0 = x1; x1 = x2; x2 = x3;
    }
    __syncthreads();
    // u_bf rows (l,c) via LDS transpose, 16B stores
    for (int f = tid; f < 64*8; f += 256) {
        int row = f >> 3, g8 = (f & 7)*8;
        if (l0 + row < L_)
            *(uint4*)(u_bf + (size_t)(b*L_ + l0 + row)*512 + c0 + g8) =
                *(const uint4*)&us[row][g8];
    }
}

// ---------------- x_proj via MFMA (fragments direct from global) + fused dt_proj ----
__global__ __launch_bounds__(256) void xproj_dt_kernel(
    const ushort_t* __restrict__ U, const ushort_t* __restrict__ XWb,
    const float* __restrict__ DTW, const float* __restrict__ DTB,
    float* __restrict__ bn, float* __restrict__ cn, float* __restrict__ dtn)
{
    __shared__ float ps[4*16*48];
    __shared__ float dtr_s[16][16];
    const int l0 = blockIdx.x * 16, b = blockIdx.y;
    const int tid = threadIdx.x;
    const int lane = tid & 63, w = tid >> 6;
    const int qd = lane >> 4, l16 = lane & 15;
    const ushort_t* arow = U + ((size_t)(b*L_) + l0 + l16)*512;
    f32x4 acc[3] = {};
    #pragma unroll
    for (int step = 0; step < 4; step++) {
        int k = w*128 + step*32 + qd*8;
        bf16x8 af = *(const bf16x8*)(arow + k);
        #pragma unroll
        for (int j = 0; j < 3; j++) {
            bf16x8 bf = *(const bf16x8*)(XWb + (size_t)(j*16 + l16)*512 + k);
            acc[j] = __builtin_amdgcn_mfma_f32_16x16x32_bf16(af, bf, acc[j], 0, 0, 0);
        }
    }
    #pragma unroll
    for (int j = 0; j < 3; j++) {
        #pragma unroll
        for (int r = 0; r < 4; r++)
            ps[(w*16 + qd*4 + r)*48 + j*16 + l16] = acc[j][r];
    }
    __syncthreads();
    #pragma unroll
    for (int e = tid; e < 768; e += 256)
        ps[e] = ps[e] + ps[768 + e] + ps[1536 + e] + ps[2304 + e];
    __syncthreads();
    {
        int row = tid >> 4, n = tid & 15;
        dtr_s[row][n] = ps[row*48 + n];
        size_t base = ((size_t)(b*L_) + l0 + row)*DS_ + n;
        bn[base] = ps[row*48 + 16 + n];
        cn[base] = ps[row*48 + 32 + n];
    }
    __syncthreads();
    #pragma unroll
    for (int q = 0; q < 2; q++) {
        int d = tid + q*256;
        float wreg[16];
        const float4* wp = (const float4*)(DTW + (size_t)d*16);
        #pragma unroll
        for (int k4 = 0; k4 < 4; k4++) {
            float4 v = wp[k4];
            wreg[4*k4+0] = v.x; wreg[4*k4+1] = v.y;
            wreg[4*k4+2] = v.z; wreg[4*k4+3] = v.w;
        }
        float bias = DTB[d];
        #pragma unroll
        for (int r = 0; r < 16; r++) {
            float a = bias;
            #pragma unroll
            for (int k = 0; k < 16; k++) a = fmaf(dtr_s[r][k], wreg[k], a);
            float dt = a > 20.f ? a : log1pf(__expf(a));
            dtn[((size_t)(b*L_) + l0 + r)*DI_ + d] = dt;
        }
    }
}

// ---------------- chunked selective scan, thread-per-d (no cross-lane) ----------
__global__ __launch_bounds__(128) void scan_phase1(
    const float* __restrict__ dtn, const ushort_t* __restrict__ u_bf,
    const float* __restrict__ bn, const float* __restrict__ Alog,
    float* __restrict__ send, float* __restrict__ aprod)
{
    __shared__ float b_sh[CL_*DS_];
    const int c = blockIdx.x, qy = blockIdx.y, b = blockIdx.z;
    const int tid = threadIdx.x;
    const int d = qy*128 + tid;
    const int l0 = c*CL_;
    for (int f = tid; f < CL_*DS_; f += 128)
        b_sh[f] = bn[((size_t)(b*L_) + l0)*DS_ + f];
    float Ac[DS_], s[DS_], ap[DS_];
    const float* ar = Alog + (size_t)d*DS_;
    #pragma unroll
    for (int n = 0; n < DS_; n++) { Ac[n] = -__expf(ar[n]); s[n] = 0.f; ap[n] = 1.f; }
    __syncthreads();
    const float*    dtp = dtn  + ((size_t)(b*L_ + l0))*DI_ + d;
    const ushort_t* up  = u_bf + ((size_t)(b*L_ + l0))*DI_ + d;
    for (int l = 0; l < CL_; l++) {
        float dt = dtp[(size_t)l*DI_];
        float u  = bf2f(up[(size_t)l*DI_]);
        float dtu = dt*u;
        float bv[DS_];
        #pragma unroll
        for (int n4 = 0; n4 < 4; n4++)
            *(float4*)&bv[4*n4] = *(const float4*)&b_sh[l*DS_ + 4*n4];
        #pragma unroll
        for (int n = 0; n < DS_; n++) {
            float e = __expf(dt*Ac[n]);
            s[n] = fmaf(e, s[n], dtu*bv[n]);
            ap[n] *= e;
        }
    }
    size_t base = (((size_t)c*B_ + b)*DI_ + d)*DS_;
    #pragma unroll
    for (int n4 = 0; n4 < 4; n4++) {
        *(float4*)(send  + base + 4*n4) = *(float4*)&s[4*n4];
        *(float4*)(aprod + base + 4*n4) = *(float4*)&ap[4*n4];
    }
}

__global__ __launch_bounds__(256) void scan_phase2(
    float* __restrict__ send, const float* __restrict__ aprod)
{
    int t = blockIdx.x*256 + threadIdx.x;   // B_*DI_*DS_ = 16384 threads
    float s = 0.f;
    for (int c = 0; c < NC_; c++) {
        size_t idx = (size_t)c*(B_*DI_*DS_) + t;         // coalesced per c
        float tmp = send[idx];
        send[idx] = s;
        s = fmaf(aprod[idx], s, tmp);
    }
}

// Phase 3: re-run chunk with incoming state; fuse (y + u*D)*silu(z) -> bf16.
__global__ __launch_bounds__(128) void scan_phase3(
    const float* __restrict__ dtn, const ushort_t* __restrict__ u_bf,
    const float* __restrict__ bn, const float* __restrict__ cn,
    const float* __restrict__ Alog, const float* __restrict__ Dv,
    const float* __restrict__ sin_, const ushort_t* __restrict__ xz,
    ushort_t* __restrict__ ysb)
{
    __shared__ float b_sh[CL_*DS_];
    __shared__ float c_sh[CL_*DS_];
    const int c = blockIdx.x, qy = blockIdx.y, b = blockIdx.z;
    const int tid = threadIdx.x;
    const int d = qy*128 + tid;
    const int l0 = c*CL_;
    for (int f = tid; f < CL_*DS_; f += 128) {
        size_t src = ((size_t)(b*L_) + l0)*DS_ + f;
        b_sh[f] = bn[src];
        c_sh[f] = cn[src];
    }
    float Ac[DS_], s[DS_];
    const float* ar = Alog + (size_t)d*DS_;
    #pragma unroll
    for (int n = 0; n < DS_; n++) Ac[n] = -__expf(ar[n]);
    {
        size_t base = (((size_t)c*B_ + b)*DI_ + d)*DS_;
        #pragma unroll
        for (int n4 = 0; n4 < 4; n4++)
            *(float4*)&s[4*n4] = *(const float4*)(sin_ + base + 4*n4);
    }
    const float Dd = Dv[d];
    __syncthreads();
    const float*    dtp = dtn  + ((size_t)(b*L_ + l0))*DI_ + d;
    const ushort_t* up  = u_bf + ((size_t)(b*L_ + l0))*DI_ + d;
    const ushort_t* zp  = xz   + ((size_t)(b*L_ + l0))*1024 + 512 + d;
    ushort_t*       yo  = ysb  + ((size_t)(b*L_ + l0))*DI_ + d;
    for (int l = 0; l < CL_; l++) {
        float dt = dtp[(size_t)l*DI_];
        float u  = bf2f(up[(size_t)l*DI_]);
        float z  = bf2f(zp[(size_t)l*1024]);
        float dtu = dt*u;
        float bv[DS_], cv[DS_];
        #pragma unroll
        for (int n4 = 0; n4 < 4; n4++) {
            *(float4*)&bv[4*n4] = *(const float4*)&b_sh[l*DS_ + 4*n4];
            *(float4*)&cv[4*n4] = *(const float4*)&c_sh[l*DS_ + 4*n4];
        }
        float y = u*Dd;
        #pragma unroll
        for (int n = 0; n < DS_; n++) {
            float e = __expf(dt*Ac[n]);
            s[n] = fmaf(e, s[n], dtu*bv[n]);
            y = fmaf(s[n], cv[n], y);
        }
        yo[(size_t)l*DI_] = f2bf(y * siluf(z));
    }
}

// ---------------- final LN + head dot ----------------
__global__ __launch_bounds__(256) void final_kernel(
    const float* __restrict__ h, const float* __restrict__ fw,
    const float* __restrict__ fb, const float* __restrict__ hw,
    const float* __restrict__ hb, float* __restrict__ out)
{
    __shared__ float sm[4];
    int row = blockIdx.x, tid = threadIdx.x;
    float v = h[(size_t)row*DM_ + tid];
    float s = v;
    #pragma unroll
    for (int o = 32; o > 0; o >>= 1) s += __shfl_down(s, o);
    if ((tid & 63) == 0) sm[tid >> 6] = s;
    __syncthreads();
    float mu = (sm[0]+sm[1]+sm[2]+sm[3]) * (1.f/DM_);
    __syncthreads();
    float dv = v - mu;
    float q = dv*dv;
    #pragma unroll
    for (int o = 32; o > 0; o >>= 1) q += __shfl_down(q, o);
    if ((tid & 63) == 0) sm[tid >> 6] = q;
    __syncthreads();
    float var = (sm[0]+sm[1]+sm[2]+sm[3]) * (1.f/DM_);
    float nv = dv * rsqrtf(var + 1e-5f) * fw[tid] + fb[tid];
    float p = nv * hw[tid];
    __syncthreads();
    #pragma unroll
    for (int o = 32; o > 0; o >>= 1) p += __shfl_down(p, o);
    if ((tid & 63) == 0) sm[tid >> 6] = p;
    __syncthreads();
    if (tid == 0) out[row] = sm[0]+sm[1]+sm[2]+sm[3] + hb[0];
}

extern "C" void kernel_launch(void* const* d_in, const int* in_sizes, int n_in,
                              void* d_out, int out_size, void* d_ws, size_t ws_size,
                              hipStream_t stream)
{
    const float* x    = (const float*)d_in[0];
    const float* biw  = (const float*)d_in[1];
    const float* bib  = (const float*)d_in[2];
    const float* ge   = (const float*)d_in[3];
    const float* me   = (const float*)d_in[4];
    const float* lnw  = (const float*)d_in[5];
    const float* lnb  = (const float*)d_in[6];
    const float* ipw  = (const float*)d_in[7];
    const float* cw   = (const float*)d_in[8];
    const float* cb   = (const float*)d_in[9];
    const float* xpw  = (const float*)d_in[10];
    const float* dtw  = (const float*)d_in[11];
    const float* dtb  = (const float*)d_in[12];
    const float* alog = (const float*)d_in[13];
    const float* Dv   = (const float*)d_in[14];
    const float* opw  = (const float*)d_in[15];
    const float* fw   = (const float*)d_in[16];
    const float* fb   = (const float*)d_in[17];
    const float* hw   = (const float*)d_in[18];
    const float* hb   = (const float*)d_in[19];
    float* out = (float*)d_out;

    // workspace layout (float units; 16B-aligned); ~42 MB
    float* ws  = (float*)d_ws;
    float* h     = ws;                                   // 1,048,576 f
    float* scr   = h + (size_t)BLP_*DM_;                 // 655,360 f (hnb)
    float* dtn   = scr + 655360;                         // 2,048,000 f (b,l,d)
    float* bn    = dtn + (size_t)B_*L_*DI_;              // 64,000 f (b,l,n)
    float* cn    = bn + (size_t)B_*L_*DS_;               // 64,000 f
    float* send  = cn + (size_t)B_*L_*DS_;               // 819,200 f
    float* aprod = send + (size_t)B_*DI_*DS_*NC_;        // 819,200 f
    ushort_t* xz_bf = (ushort_t*)(aprod + (size_t)B_*DI_*DS_*NC_); // BLP_*1024 us
    ushort_t* u_bf  = xz_bf + (size_t)BLP_*1024;         // BLP_*DI_ us
    ushort_t* ysbb  = u_bf + (size_t)BLP_*DI_;           // BLP_*DI_ us
    ushort_t* ipwb  = ysbb + (size_t)BLP_*DI_;           // NL_*1024*DM_ us
    ushort_t* opwb  = ipwb + (size_t)NL_*1024*DM_;       // NL_*DM_*DI_ us
    ushort_t* xpwb  = opwb + (size_t)NL_*DM_*DI_;        // NL_*48*512 us
    ushort_t* hnb   = (ushort_t*)scr;                    // BLP_*DM_ us

    // convert all weights to bf16 in one launch
    const int N0 = NL_*1024*DM_/4, N1 = NL_*DM_*DI_/4, N2 = NL_*48*512/4;
    f2bf3_kernel<<<(N0+N1+N2 + 255)/256, 256, 0, stream>>>(
        ipw, opw, xpw, ipwb, opwb, xpwb, N0, N1, N2);

    embed_kernel<<<BL_, 256, 0, stream>>>(x, biw, bib, ge, me, h);
    for (int i = 0; i < NL_; i++) {
        ln_kernel<<<BL_, 256, 0, stream>>>(h, lnw + i*DM_, lnb + i*DM_, hnb);
        gemm_mfma<false, ushort_t><<<dim3(BLP_/128, 1024/128), 256, 0, stream>>>(
            hnb, ipwb + (size_t)i*1024*DM_, xz_bf, 1024, DM_);
        conv_silu_kernel<<<dim3(32, 8, B_), 256, 0, stream>>>(
            xz_bf, cw + i*DI_*4, cb + i*DI_, u_bf);
        xproj_dt_kernel<<<dim3(125, B_), 256, 0, stream>>>(
            u_bf, xpwb + (size_t)i*48*512, dtw + (size_t)i*DI_*16, dtb + i*DI_,
            bn, cn, dtn);
        scan_phase1<<<dim3(NC_, DI_/128, B_), 128, 0, stream>>>(
            dtn, u_bf, bn, alog + (size_t)i*DI_*DS_, send, aprod);
        scan_phase2<<<B_*DI_*DS_/256, 256, 0, stream>>>(send, aprod);
        scan_phase3<<<dim3(NC_, DI_/128, B_), 128, 0, stream>>>(
            dtn, u_bf, bn, cn, alog + (size_t)i*DI_*DS_, Dv + i*DI_,
            send, xz_bf, ysbb);
        gemm_mfma<true, float><<<dim3(BLP_/128, DM_/128), 256, 0, stream>>>(
            ysbb, opwb + (size_t)i*DM_*DI_, h, DM_, DI_);
    }
    final_kernel<<<BL_, 256, 0, stream>>>(h, fw, fb, hw, hb, out);
}

// Round 11
// 520.547 us; speedup vs baseline: 1.1198x; 1.1198x over previous
//
#include <hip/hip_runtime.h>
#include <math.h>

#define B_  2
#define L_  2000
#define DM_ 256
#define DI_ 512
#define DS_ 16
#define NL_ 4
#define BL_ (B_*L_)     // 4000
#define BLP_ 4096       // rows padded to multiple of 64
#define NC_ 100         // scan chunks (100 -> 800 blocks: occupancy matters more
#define CL_ 20          //   than carry traffic; NC=50 regressed R9 by ~55us)

typedef unsigned short ushort_t;
typedef __attribute__((ext_vector_type(8))) short bf16x8;
typedef __attribute__((ext_vector_type(4))) float f32x4;

__device__ __forceinline__ float siluf(float x) {
    return x / (1.f + __expf(-x));
}

__device__ __forceinline__ ushort_t f2bf(float x) {
    unsigned int u = __float_as_uint(x);
    unsigned int r = (u + 0x7FFFu + ((u >> 16) & 1u)) >> 16;
    return (ushort_t)r;
}

__device__ __forceinline__ float bf2f(ushort_t v) {
    return __uint_as_float(((unsigned int)v) << 16);
}

// ---------------- fp32 -> bf16 conversion, 3 segments in one launch ----------------
__global__ __launch_bounds__(256) void f2bf3_kernel(
    const float* __restrict__ s0, const float* __restrict__ s1,
    const float* __restrict__ s2, ushort_t* __restrict__ d0,
    ushort_t* __restrict__ d1, ushort_t* __restrict__ d2,
    int N0, int N1, int N2)
{
    int i = blockIdx.x*256 + threadIdx.x;
    const float* s; ushort_t* d; int j;
    if (i < N0)           { s = s0; d = d0; j = i; }
    else if (i < N0+N1)   { s = s1; d = d1; j = i - N0; }
    else if (i < N0+N1+N2){ s = s2; d = d2; j = i - N0 - N1; }
    else return;
    float4 v = *(const float4*)(s + 4*j);
    ushort_t o[4] = {f2bf(v.x), f2bf(v.y), f2bf(v.z), f2bf(v.w)};
    *(ushort2*)(d + 4*j)     = *(ushort2*)&o[0];
    *(ushort2*)(d + 4*j + 2) = *(ushort2*)&o[2];
}

// ---------------- embed: h = x*biw + bib + gene_emb + mod_emb ----------------
__global__ __launch_bounds__(256) void embed_kernel(
    const float* __restrict__ x, const float* __restrict__ biw,
    const float* __restrict__ bib, const float* __restrict__ ge,
    const float* __restrict__ me, float* __restrict__ h)
{
    int bl = blockIdx.x, d = threadIdx.x;
    int l = bl % L_;
    h[(size_t)bl*DM_ + d] = x[bl]*biw[d] + bib[d] + ge[(size_t)l*DM_ + d] + me[d];
}

// ---------------- layernorm over D_MODEL=256 -> bf16 output ----------------
__global__ __launch_bounds__(256) void ln_kernel(
    const float* __restrict__ h, const float* __restrict__ w,
    const float* __restrict__ b, ushort_t* __restrict__ out)
{
    __shared__ float sm[4];
    int row = blockIdx.x, tid = threadIdx.x;
    float v = h[(size_t)row*DM_ + tid];
    float s = v;
    #pragma unroll
    for (int o = 32; o > 0; o >>= 1) s += __shfl_down(s, o);
    if ((tid & 63) == 0) sm[tid >> 6] = s;
    __syncthreads();
    float mu = (sm[0]+sm[1]+sm[2]+sm[3]) * (1.f/DM_);
    __syncthreads();
    float d = v - mu;
    float q = d*d;
    #pragma unroll
    for (int o = 32; o > 0; o >>= 1) q += __shfl_down(q, o);
    if ((tid & 63) == 0) sm[tid >> 6] = q;
    __syncthreads();
    float var = (sm[0]+sm[1]+sm[2]+sm[3]) * (1.f/DM_);
    out[(size_t)row*DM_ + tid] = f2bf(d * rsqrtf(var + 1e-5f) * w[tid] + b[tid]);
}

// ---------------- bf16 MFMA GEMM: C[m,n] (+)= sum_k A[m,k]*W[n,k] ----------------
// OutT = float (ACCUM +=) or ushort_t (bf16 store).
template<bool ACCUM, typename OutT>
__global__ __launch_bounds__(256) void gemm_mfma(
    const ushort_t* __restrict__ A, const ushort_t* __restrict__ W,
    OutT* __restrict__ C, int ldc, int K)
{
    __shared__ ushort_t a_s[128*64];
    __shared__ ushort_t b_s[128*64];
    const int r0 = blockIdx.x*128, c0 = blockIdx.y*128;
    const int tid = threadIdx.x;
    const int lane = tid & 63, w = tid >> 6;
    const int wm = (w & 1)*64, wn = (w >> 1)*64;
    const int qd = lane >> 4, l16 = lane & 15;
    f32x4 acc[4][4] = {};
    for (int kc = 0; kc < K; kc += 64) {
        #pragma unroll
        for (int q = 0; q < 4; q++) {
            int ch = tid + 256*q;              // 0..1023
            int row = ch >> 3, col8 = (ch & 7)*8;
            *(bf16x8*)&a_s[row*64 + col8] =
                *(const bf16x8*)(A + (size_t)(r0 + row)*K + kc + col8);
            *(bf16x8*)&b_s[row*64 + col8] =
                *(const bf16x8*)(W + (size_t)(c0 + row)*K + kc + col8);
        }
        __syncthreads();
        #pragma unroll
        for (int ks = 0; ks < 2; ks++) {
            bf16x8 af[4], bf[4];
            #pragma unroll
            for (int i = 0; i < 4; i++)
                af[i] = *(const bf16x8*)&a_s[(wm + i*16 + l16)*64 + ks*32 + qd*8];
            #pragma unroll
            for (int j = 0; j < 4; j++)
                bf[j] = *(const bf16x8*)&b_s[(wn + j*16 + l16)*64 + ks*32 + qd*8];
            #pragma unroll
            for (int i = 0; i < 4; i++) {
                #pragma unroll
                for (int j = 0; j < 4; j++)
                    acc[i][j] = __builtin_amdgcn_mfma_f32_16x16x32_bf16(
                        af[i], bf[j], acc[i][j], 0, 0, 0);
            }
        }
        __syncthreads();
    }
    // C/D layout: col = lane&15, row = (lane>>4)*4 + reg
    #pragma unroll
    for (int i = 0; i < 4; i++) {
        #pragma unroll
        for (int j = 0; j < 4; j++) {
            #pragma unroll
            for (int r = 0; r < 4; r++) {
                int row = r0 + wm + i*16 + qd*4 + r;
                int col = c0 + wn + j*16 + l16;
                size_t idx = (size_t)row*ldc + col;
                if constexpr (ACCUM)                  C[idx] += acc[i][j][r];
                else if constexpr (sizeof(OutT) == 2) C[idx]  = f2bf(acc[i][j][r]);
                else                                  C[idx]  = acc[i][j][r];
            }
        }
    }
}

// ---------------- conv(4) + silu on bf16 xz; writes u_bf (b,l,c) bf16 ----------------
__global__ __launch_bounds__(256) void conv_silu_kernel(
    const ushort_t* __restrict__ xz, const float* __restrict__ cw,
    const float* __restrict__ cb, ushort_t* __restrict__ u_bf)
{
    __shared__ ushort_t xs[67][72];
    __shared__ ushort_t us[64][72];
    const int l0 = blockIdx.x * 64, c0 = blockIdx.y * 64, b = blockIdx.z;
    const int tid = threadIdx.x;
    // stage xz tile rows l0-3 .. l0+63 (64 c each, bf16)
    for (int f = tid; f < 67*8; f += 256) {
        int row = f >> 3, c8 = (f & 7) * 8;
        int l = l0 - 3 + row;
        uint4 v = {0u, 0u, 0u, 0u};
        if (l >= 0 && l < L_)
            v = *(const uint4*)(xz + (size_t)(b*L_ + l)*1024 + c0 + c8);
        *(uint4*)&xs[row][c8] = v;
    }
    __syncthreads();
    // conv: thread -> fixed c, 16 consecutive l
    const int c_loc = tid & 63, lq = tid >> 6;
    const int c = c0 + c_loc;
    float4 wv = *(const float4*)(cw + c*4);
    float bias = cb[c];
    float x0 = bf2f(xs[lq*16 + 0][c_loc]);
    float x1 = bf2f(xs[lq*16 + 1][c_loc]);
    float x2 = bf2f(xs[lq*16 + 2][c_loc]);
    #pragma unroll
    for (int j = 0; j < 16; j++) {
        float x3 = bf2f(xs[lq*16 + 3 + j][c_loc]);
        float v = fmaf(x0, wv.x, fmaf(x1, wv.y, fmaf(x2, wv.z, fmaf(x3, wv.w, bias))));
        us[lq*16 + j][c_loc] = f2bf(siluf(v));
        x0 = x1; x1 = x2; x2 = x3;
    }
    __syncthreads();
    // u_bf rows (l,c) via LDS transpose, 16B stores
    for (int f = tid; f < 64*8; f += 256) {
        int row = f >> 3, g8 = (f & 7)*8;
        if (l0 + row < L_)
            *(uint4*)(u_bf + (size_t)(b*L_ + l0 + row)*512 + c0 + g8) =
                *(const uint4*)&us[row][g8];
    }
}

// ---------------- x_proj via MFMA (fragments direct from global) + fused dt_proj ----
__global__ __launch_bounds__(256) void xproj_dt_kernel(
    const ushort_t* __restrict__ U, const ushort_t* __restrict__ XWb,
    const float* __restrict__ DTW, const float* __restrict__ DTB,
    float* __restrict__ bn, float* __restrict__ cn, float* __restrict__ dtn)
{
    __shared__ float ps[4*16*48];
    __shared__ float dtr_s[16][16];
    const int l0 = blockIdx.x * 16, b = blockIdx.y;
    const int tid = threadIdx.x;
    const int lane = tid & 63, w = tid >> 6;
    const int qd = lane >> 4, l16 = lane & 15;
    const ushort_t* arow = U + ((size_t)(b*L_) + l0 + l16)*512;
    f32x4 acc[3] = {};
    #pragma unroll
    for (int step = 0; step < 4; step++) {
        int k = w*128 + step*32 + qd*8;
        bf16x8 af = *(const bf16x8*)(arow + k);
        #pragma unroll
        for (int j = 0; j < 3; j++) {
            bf16x8 bf = *(const bf16x8*)(XWb + (size_t)(j*16 + l16)*512 + k);
            acc[j] = __builtin_amdgcn_mfma_f32_16x16x32_bf16(af, bf, acc[j], 0, 0, 0);
        }
    }
    #pragma unroll
    for (int j = 0; j < 3; j++) {
        #pragma unroll
        for (int r = 0; r < 4; r++)
            ps[(w*16 + qd*4 + r)*48 + j*16 + l16] = acc[j][r];
    }
    __syncthreads();
    #pragma unroll
    for (int e = tid; e < 768; e += 256)
        ps[e] = ps[e] + ps[768 + e] + ps[1536 + e] + ps[2304 + e];
    __syncthreads();
    {
        int row = tid >> 4, n = tid & 15;
        dtr_s[row][n] = ps[row*48 + n];
        size_t base = ((size_t)(b*L_) + l0 + row)*DS_ + n;
        bn[base] = ps[row*48 + 16 + n];
        cn[base] = ps[row*48 + 32 + n];
    }
    __syncthreads();
    #pragma unroll
    for (int q = 0; q < 2; q++) {
        int d = tid + q*256;
        float wreg[16];
        const float4* wp = (const float4*)(DTW + (size_t)d*16);
        #pragma unroll
        for (int k4 = 0; k4 < 4; k4++) {
            float4 v = wp[k4];
            wreg[4*k4+0] = v.x; wreg[4*k4+1] = v.y;
            wreg[4*k4+2] = v.z; wreg[4*k4+3] = v.w;
        }
        float bias = DTB[d];
        #pragma unroll
        for (int r = 0; r < 16; r++) {
            float a = bias;
            #pragma unroll
            for (int k = 0; k < 16; k++) a = fmaf(dtr_s[r][k], wreg[k], a);
            float dt = a > 20.f ? a : log1pf(__expf(a));
            dtn[((size_t)(b*L_) + l0 + r)*DI_ + d] = dt;
        }
    }
}

// ---------------- chunked selective scan, thread-per-d (no cross-lane) ----------
__global__ __launch_bounds__(128) void scan_phase1(
    const float* __restrict__ dtn, const ushort_t* __restrict__ u_bf,
    const float* __restrict__ bn, const float* __restrict__ Alog,
    float* __restrict__ send, float* __restrict__ aprod)
{
    __shared__ float b_sh[CL_*DS_];
    const int c = blockIdx.x, qy = blockIdx.y, b = blockIdx.z;
    const int tid = threadIdx.x;
    const int d = qy*128 + tid;
    const int l0 = c*CL_;
    for (int f = tid; f < CL_*DS_; f += 128)
        b_sh[f] = bn[((size_t)(b*L_) + l0)*DS_ + f];
    float Ac[DS_], s[DS_], ap[DS_];
    const float* ar = Alog + (size_t)d*DS_;
    #pragma unroll
    for (int n = 0; n < DS_; n++) { Ac[n] = -__expf(ar[n]); s[n] = 0.f; ap[n] = 1.f; }
    __syncthreads();
    const float*    dtp = dtn  + ((size_t)(b*L_ + l0))*DI_ + d;
    const ushort_t* up  = u_bf + ((size_t)(b*L_ + l0))*DI_ + d;
    for (int l = 0; l < CL_; l++) {
        float dt = dtp[(size_t)l*DI_];
        float u  = bf2f(up[(size_t)l*DI_]);
        float dtu = dt*u;
        float bv[DS_];
        #pragma unroll
        for (int n4 = 0; n4 < 4; n4++)
            *(float4*)&bv[4*n4] = *(const float4*)&b_sh[l*DS_ + 4*n4];
        #pragma unroll
        for (int n = 0; n < DS_; n++) {
            float e = __expf(dt*Ac[n]);
            s[n] = fmaf(e, s[n], dtu*bv[n]);
            ap[n] *= e;
        }
    }
    size_t base = (((size_t)c*B_ + b)*DI_ + d)*DS_;
    #pragma unroll
    for (int n4 = 0; n4 < 4; n4++) {
        *(float4*)(send  + base + 4*n4) = *(float4*)&s[4*n4];
        *(float4*)(aprod + base + 4*n4) = *(float4*)&ap[4*n4];
    }
}

__global__ __launch_bounds__(256) void scan_phase2(
    float* __restrict__ send, const float* __restrict__ aprod)
{
    int t = blockIdx.x*256 + threadIdx.x;   // B_*DI_*DS_ = 16384 threads
    float s = 0.f;
    for (int c = 0; c < NC_; c++) {
        size_t idx = (size_t)c*(B_*DI_*DS_) + t;         // coalesced per c
        float tmp = send[idx];
        send[idx] = s;
        s = fmaf(aprod[idx], s, tmp);
    }
}

// Phase 3: re-run chunk with incoming state; fuse (y + u*D)*silu(z) -> bf16.
__global__ __launch_bounds__(128) void scan_phase3(
    const float* __restrict__ dtn, const ushort_t* __restrict__ u_bf,
    const float* __restrict__ bn, const float* __restrict__ cn,
    const float* __restrict__ Alog, const float* __restrict__ Dv,
    const float* __restrict__ sin_, const ushort_t* __restrict__ xz,
    ushort_t* __restrict__ ysb)
{
    __shared__ float b_sh[CL_*DS_];
    __shared__ float c_sh[CL_*DS_];
    const int c = blockIdx.x, qy = blockIdx.y, b = blockIdx.z;
    const int tid = threadIdx.x;
    const int d = qy*128 + tid;
    const int l0 = c*CL_;
    for (int f = tid; f < CL_*DS_; f += 128) {
        size_t src = ((size_t)(b*L_) + l0)*DS_ + f;
        b_sh[f] = bn[src];
        c_sh[f] = cn[src];
    }
    float Ac[DS_], s[DS_];
    const float* ar = Alog + (size_t)d*DS_;
    #pragma unroll
    for (int n = 0; n < DS_; n++) Ac[n] = -__expf(ar[n]);
    {
        size_t base = (((size_t)c*B_ + b)*DI_ + d)*DS_;
        #pragma unroll
        for (int n4 = 0; n4 < 4; n4++)
            *(float4*)&s[4*n4] = *(const float4*)(sin_ + base + 4*n4);
    }
    const float Dd = Dv[d];
    __syncthreads();
    const float*    dtp = dtn  + ((size_t)(b*L_ + l0))*DI_ + d;
    const ushort_t* up  = u_bf + ((size_t)(b*L_ + l0))*DI_ + d;
    const ushort_t* zp  = xz   + ((size_t)(b*L_ + l0))*1024 + 512 + d;
    ushort_t*       yo  = ysb  + ((size_t)(b*L_ + l0))*DI_ + d;
    for (int l = 0; l < CL_; l++) {
        float dt = dtp[(size_t)l*DI_];
        float u  = bf2f(up[(size_t)l*DI_]);
        float z  = bf2f(zp[(size_t)l*1024]);
        float dtu = dt*u;
        float bv[DS_], cv[DS_];
        #pragma unroll
        for (int n4 = 0; n4 < 4; n4++) {
            *(float4*)&bv[4*n4] = *(const float4*)&b_sh[l*DS_ + 4*n4];
            *(float4*)&cv[4*n4] = *(const float4*)&c_sh[l*DS_ + 4*n4];
        }
        float y = u*Dd;
        #pragma unroll
        for (int n = 0; n < DS_; n++) {
            float e = __expf(dt*Ac[n]);
            s[n] = fmaf(e, s[n], dtu*bv[n]);
            y = fmaf(s[n], cv[n], y);
        }
        yo[(size_t)l*DI_] = f2bf(y * siluf(z));
    }
}

// ---------------- final LN + head dot ----------------
__global__ __launch_bounds__(256) void final_kernel(
    const float* __restrict__ h, const float* __restrict__ fw,
    const float* __restrict__ fb, const float* __restrict__ hw,
    const float* __restrict__ hb, float* __restrict__ out)
{
    __shared__ float sm[4];
    int row = blockIdx.x, tid = threadIdx.x;
    float v = h[(size_t)row*DM_ + tid];
    float s = v;
    #pragma unroll
    for (int o = 32; o > 0; o >>= 1) s += __shfl_down(s, o);
    if ((tid & 63) == 0) sm[tid >> 6] = s;
    __syncthreads();
    float mu = (sm[0]+sm[1]+sm[2]+sm[3]) * (1.f/DM_);
    __syncthreads();
    float dv = v - mu;
    float q = dv*dv;
    #pragma unroll
    for (int o = 32; o > 0; o >>= 1) q += __shfl_down(q, o);
    if ((tid & 63) == 0) sm[tid >> 6] = q;
    __syncthreads();
    float var = (sm[0]+sm[1]+sm[2]+sm[3]) * (1.f/DM_);
    float nv = dv * rsqrtf(var + 1e-5f) * fw[tid] + fb[tid];
    float p = nv * hw[tid];
    __syncthreads();
    #pragma unroll
    for (int o = 32; o > 0; o >>= 1) p += __shfl_down(p, o);
    if ((tid & 63) == 0) sm[tid >> 6] = p;
    __syncthreads();
    if (tid == 0) out[row] = sm[0]+sm[1]+sm[2]+sm[3] + hb[0];
}

extern "C" void kernel_launch(void* const* d_in, const int* in_sizes, int n_in,
                              void* d_out, int out_size, void* d_ws, size_t ws_size,
                              hipStream_t stream)
{
    const float* x    = (const float*)d_in[0];
    const float* biw  = (const float*)d_in[1];
    const float* bib  = (const float*)d_in[2];
    const float* ge   = (const float*)d_in[3];
    const float* me   = (const float*)d_in[4];
    const float* lnw  = (const float*)d_in[5];
    const float* lnb  = (const float*)d_in[6];
    const float* ipw  = (const float*)d_in[7];
    const float* cw   = (const float*)d_in[8];
    const float* cb   = (const float*)d_in[9];
    const float* xpw  = (const float*)d_in[10];
    const float* dtw  = (const float*)d_in[11];
    const float* dtb  = (const float*)d_in[12];
    const float* alog = (const float*)d_in[13];
    const float* Dv   = (const float*)d_in[14];
    const float* opw  = (const float*)d_in[15];
    const float* fw   = (const float*)d_in[16];
    const float* fb   = (const float*)d_in[17];
    const float* hw   = (const float*)d_in[18];
    const float* hb   = (const float*)d_in[19];
    float* out = (float*)d_out;

    // workspace layout (float units; 16B-aligned); ~49 MB
    float* ws  = (float*)d_ws;
    float* h     = ws;                                   // 1,048,576 f
    float* scr   = h + (size_t)BLP_*DM_;                 // 655,360 f (hnb)
    float* dtn   = scr + 655360;                         // 2,048,000 f (b,l,d)
    float* bn    = dtn + (size_t)B_*L_*DI_;              // 64,000 f (b,l,n)
    float* cn    = bn + (size_t)B_*L_*DS_;               // 64,000 f
    float* send  = cn + (size_t)B_*L_*DS_;               // 1,638,400 f
    float* aprod = send + (size_t)B_*DI_*DS_*NC_;        // 1,638,400 f
    ushort_t* xz_bf = (ushort_t*)(aprod + (size_t)B_*DI_*DS_*NC_); // BLP_*1024 us
    ushort_t* u_bf  = xz_bf + (size_t)BLP_*1024;         // BLP_*DI_ us
    ushort_t* ysbb  = u_bf + (size_t)BLP_*DI_;           // BLP_*DI_ us
    ushort_t* ipwb  = ysbb + (size_t)BLP_*DI_;           // NL_*1024*DM_ us
    ushort_t* opwb  = ipwb + (size_t)NL_*1024*DM_;       // NL_*DM_*DI_ us
    ushort_t* xpwb  = opwb + (size_t)NL_*DM_*DI_;        // NL_*48*512 us
    ushort_t* hnb   = (ushort_t*)scr;                    // BLP_*DM_ us

    // convert all weights to bf16 in one launch
    const int N0 = NL_*1024*DM_/4, N1 = NL_*DM_*DI_/4, N2 = NL_*48*512/4;
    f2bf3_kernel<<<(N0+N1+N2 + 255)/256, 256, 0, stream>>>(
        ipw, opw, xpw, ipwb, opwb, xpwb, N0, N1, N2);

    embed_kernel<<<BL_, 256, 0, stream>>>(x, biw, bib, ge, me, h);
    for (int i = 0; i < NL_; i++) {
        ln_kernel<<<BL_, 256, 0, stream>>>(h, lnw + i*DM_, lnb + i*DM_, hnb);
        gemm_mfma<false, ushort_t><<<dim3(BLP_/128, 1024/128), 256, 0, stream>>>(
            hnb, ipwb + (size_t)i*1024*DM_, xz_bf, 1024, DM_);
        conv_silu_kernel<<<dim3(32, 8, B_), 256, 0, stream>>>(
            xz_bf, cw + i*DI_*4, cb + i*DI_, u_bf);
        xproj_dt_kernel<<<dim3(125, B_), 256, 0, stream>>>(
            u_bf, xpwb + (size_t)i*48*512, dtw + (size_t)i*DI_*16, dtb + i*DI_,
            bn, cn, dtn);
        scan_phase1<<<dim3(NC_, DI_/128, B_), 128, 0, stream>>>(
            dtn, u_bf, bn, alog + (size_t)i*DI_*DS_, send, aprod);
        scan_phase2<<<B_*DI_*DS_/256, 256, 0, stream>>>(send, aprod);
        scan_phase3<<<dim3(NC_, DI_/128, B_), 128, 0, stream>>>(
            dtn, u_bf, bn, cn, alog + (size_t)i*DI_*DS_, Dv + i*DI_,
            send, xz_bf, ysbb);
        gemm_mfma<true, float><<<dim3(BLP_/128, DM_/128), 256, 0, stream>>>(
            ysbb, opwb + (size_t)i*DM_*DI_, h, DM_, DI_);
    }
    final_kernel<<<BL_, 256, 0, stream>>>(h, fw, fb, hw, hb, out);
}

// Round 12
// 510.458 us; speedup vs baseline: 1.1419x; 1.0198x over previous
//
#include <hip/hip_runtime.h>
#include <math.h>

#define B_  2
#define L_  2000
#define DM_ 256
#define DI_ 512
#define DS_ 16
#define NL_ 4
#define BL_ (B_*L_)     // 4000
#define BLP_ 4096       // rows padded to multiple of 64
#define NC_ 100         // scan chunks (NC=50 regressed R9: occupancy > carry traffic)
#define CL_ 20          // chunk length

typedef unsigned short ushort_t;
typedef __attribute__((ext_vector_type(8))) short bf16x8;
typedef __attribute__((ext_vector_type(4))) float f32x4;

__device__ __forceinline__ float siluf(float x) {
    return x / (1.f + __expf(-x));
}

__device__ __forceinline__ ushort_t f2bf(float x) {
    unsigned int u = __float_as_uint(x);
    unsigned int r = (u + 0x7FFFu + ((u >> 16) & 1u)) >> 16;
    return (ushort_t)r;
}

__device__ __forceinline__ float bf2f(ushort_t v) {
    return __uint_as_float(((unsigned int)v) << 16);
}

// ---------------- fp32 -> bf16 conversion, 3 segments in one launch ----------------
__global__ __launch_bounds__(256) void f2bf3_kernel(
    const float* __restrict__ s0, const float* __restrict__ s1,
    const float* __restrict__ s2, ushort_t* __restrict__ d0,
    ushort_t* __restrict__ d1, ushort_t* __restrict__ d2,
    int N0, int N1, int N2)
{
    int i = blockIdx.x*256 + threadIdx.x;
    const float* s; ushort_t* d; int j;
    if (i < N0)           { s = s0; d = d0; j = i; }
    else if (i < N0+N1)   { s = s1; d = d1; j = i - N0; }
    else if (i < N0+N1+N2){ s = s2; d = d2; j = i - N0 - N1; }
    else return;
    float4 v = *(const float4*)(s + 4*j);
    ushort_t o[4] = {f2bf(v.x), f2bf(v.y), f2bf(v.z), f2bf(v.w)};
    *(ushort2*)(d + 4*j)     = *(ushort2*)&o[0];
    *(ushort2*)(d + 4*j + 2) = *(ushort2*)&o[2];
}

// ---------------- embed: h = x*biw + bib + gene_emb + mod_emb ----------------
__global__ __launch_bounds__(256) void embed_kernel(
    const float* __restrict__ x, const float* __restrict__ biw,
    const float* __restrict__ bib, const float* __restrict__ ge,
    const float* __restrict__ me, float* __restrict__ h)
{
    int bl = blockIdx.x, d = threadIdx.x;
    int l = bl % L_;
    h[(size_t)bl*DM_ + d] = x[bl]*biw[d] + bib[d] + ge[(size_t)l*DM_ + d] + me[d];
}

// ---------------- layernorm over D_MODEL=256 -> bf16 output ----------------
__global__ __launch_bounds__(256) void ln_kernel(
    const float* __restrict__ h, const float* __restrict__ w,
    const float* __restrict__ b, ushort_t* __restrict__ out)
{
    __shared__ float sm[4];
    int row = blockIdx.x, tid = threadIdx.x;
    float v = h[(size_t)row*DM_ + tid];
    float s = v;
    #pragma unroll
    for (int o = 32; o > 0; o >>= 1) s += __shfl_down(s, o);
    if ((tid & 63) == 0) sm[tid >> 6] = s;
    __syncthreads();
    float mu = (sm[0]+sm[1]+sm[2]+sm[3]) * (1.f/DM_);
    __syncthreads();
    float d = v - mu;
    float q = d*d;
    #pragma unroll
    for (int o = 32; o > 0; o >>= 1) q += __shfl_down(q, o);
    if ((tid & 63) == 0) sm[tid >> 6] = q;
    __syncthreads();
    float var = (sm[0]+sm[1]+sm[2]+sm[3]) * (1.f/DM_);
    out[(size_t)row*DM_ + tid] = f2bf(d * rsqrtf(var + 1e-5f) * w[tid] + b[tid]);
}

// ---------------- bf16 MFMA GEMM: C[m,n] (+)= sum_k A[m,k]*W[n,k] ----------------
// OutT = float (ACCUM +=) or ushort_t (bf16 store).
template<bool ACCUM, typename OutT>
__global__ __launch_bounds__(256) void gemm_mfma(
    const ushort_t* __restrict__ A, const ushort_t* __restrict__ W,
    OutT* __restrict__ C, int ldc, int K)
{
    __shared__ ushort_t a_s[128*64];
    __shared__ ushort_t b_s[128*64];
    const int r0 = blockIdx.x*128, c0 = blockIdx.y*128;
    const int tid = threadIdx.x;
    const int lane = tid & 63, w = tid >> 6;
    const int wm = (w & 1)*64, wn = (w >> 1)*64;
    const int qd = lane >> 4, l16 = lane & 15;
    f32x4 acc[4][4] = {};
    for (int kc = 0; kc < K; kc += 64) {
        #pragma unroll
        for (int q = 0; q < 4; q++) {
            int ch = tid + 256*q;              // 0..1023
            int row = ch >> 3, col8 = (ch & 7)*8;
            *(bf16x8*)&a_s[row*64 + col8] =
                *(const bf16x8*)(A + (size_t)(r0 + row)*K + kc + col8);
            *(bf16x8*)&b_s[row*64 + col8] =
                *(const bf16x8*)(W + (size_t)(c0 + row)*K + kc + col8);
        }
        __syncthreads();
        #pragma unroll
        for (int ks = 0; ks < 2; ks++) {
            bf16x8 af[4], bf[4];
            #pragma unroll
            for (int i = 0; i < 4; i++)
                af[i] = *(const bf16x8*)&a_s[(wm + i*16 + l16)*64 + ks*32 + qd*8];
            #pragma unroll
            for (int j = 0; j < 4; j++)
                bf[j] = *(const bf16x8*)&b_s[(wn + j*16 + l16)*64 + ks*32 + qd*8];
            #pragma unroll
            for (int i = 0; i < 4; i++) {
                #pragma unroll
                for (int j = 0; j < 4; j++)
                    acc[i][j] = __builtin_amdgcn_mfma_f32_16x16x32_bf16(
                        af[i], bf[j], acc[i][j], 0, 0, 0);
            }
        }
        __syncthreads();
    }
    // C/D layout: col = lane&15, row = (lane>>4)*4 + reg
    #pragma unroll
    for (int i = 0; i < 4; i++) {
        #pragma unroll
        for (int j = 0; j < 4; j++) {
            #pragma unroll
            for (int r = 0; r < 4; r++) {
                int row = r0 + wm + i*16 + qd*4 + r;
                int col = c0 + wn + j*16 + l16;
                size_t idx = (size_t)row*ldc + col;
                if constexpr (ACCUM)                  C[idx] += acc[i][j][r];
                else if constexpr (sizeof(OutT) == 2) C[idx]  = f2bf(acc[i][j][r]);
                else                                  C[idx]  = acc[i][j][r];
            }
        }
    }
}

// ---------------- conv(4) + silu on bf16 xz; writes u_bf (b,l,c) bf16 ----------------
__global__ __launch_bounds__(256) void conv_silu_kernel(
    const ushort_t* __restrict__ xz, const float* __restrict__ cw,
    const float* __restrict__ cb, ushort_t* __restrict__ u_bf)
{
    __shared__ ushort_t xs[67][72];
    __shared__ ushort_t us[64][72];
    const int l0 = blockIdx.x * 64, c0 = blockIdx.y * 64, b = blockIdx.z;
    const int tid = threadIdx.x;
    // stage xz tile rows l0-3 .. l0+63 (64 c each, bf16)
    for (int f = tid; f < 67*8; f += 256) {
        int row = f >> 3, c8 = (f & 7) * 8;
        int l = l0 - 3 + row;
        uint4 v = {0u, 0u, 0u, 0u};
        if (l >= 0 && l < L_)
            v = *(const uint4*)(xz + (size_t)(b*L_ + l)*1024 + c0 + c8);
        *(uint4*)&xs[row][c8] = v;
    }
    __syncthreads();
    // conv: thread -> fixed c, 16 consecutive l
    const int c_loc = tid & 63, lq = tid >> 6;
    const int c = c0 + c_loc;
    float4 wv = *(const float4*)(cw + c*4);
    float bias = cb[c];
    float x0 = bf2f(xs[lq*16 + 0][c_loc]);
    float x1 = bf2f(xs[lq*16 + 1][c_loc]);
    float x2 = bf2f(xs[lq*16 + 2][c_loc]);
    #pragma unroll
    for (int j = 0; j < 16; j++) {
        float x3 = bf2f(xs[lq*16 + 3 + j][c_loc]);
        float v = fmaf(x0, wv.x, fmaf(x1, wv.y, fmaf(x2, wv.z, fmaf(x3, wv.w, bias))));
        us[lq*16 + j][c_loc] = f2bf(siluf(v));
        x0 = x1; x1 = x2; x2 = x3;
    }
    __syncthreads();
    // u_bf rows (l,c) via LDS transpose, 16B stores
    for (int f = tid; f < 64*8; f += 256) {
        int row = f >> 3, g8 = (f & 7)*8;
        if (l0 + row < L_)
            *(uint4*)(u_bf + (size_t)(b*L_ + l0 + row)*512 + c0 + g8) =
                *(const uint4*)&us[row][g8];
    }
}

// ---------------- x_proj via MFMA, 8-way K-split (512 thr) + fused dt_proj ----------
// grid(125, B_), block 512 = 8 waves, wave w covers K in [64w, 64w+64).
// Per wave: 8 global 16B loads + 6 MFMA. LDS reduce over 8 partials (24KB).
// dt_proj: thread d = tid (512 == DI), 16 rows, softplus, coalesced stores.
__global__ __launch_bounds__(512) void xproj_dt_kernel(
    const ushort_t* __restrict__ U, const ushort_t* __restrict__ XWb,
    const float* __restrict__ DTW, const float* __restrict__ DTB,
    float* __restrict__ bn, float* __restrict__ cn, float* __restrict__ dtn)
{
    __shared__ float ps[8*16*48];
    __shared__ float dtr_s[16][16];
    const int l0 = blockIdx.x * 16, b = blockIdx.y;
    const int tid = threadIdx.x;
    const int lane = tid & 63, w = tid >> 6;     // w = 0..7
    const int qd = lane >> 4, l16 = lane & 15;
    const ushort_t* arow = U + ((size_t)(b*L_) + l0 + l16)*512;
    f32x4 acc[3] = {};
    #pragma unroll
    for (int step = 0; step < 2; step++) {
        int k = w*64 + step*32 + qd*8;
        bf16x8 af = *(const bf16x8*)(arow + k);
        #pragma unroll
        for (int j = 0; j < 3; j++) {
            bf16x8 bf = *(const bf16x8*)(XWb + (size_t)(j*16 + l16)*512 + k);
            acc[j] = __builtin_amdgcn_mfma_f32_16x16x32_bf16(af, bf, acc[j], 0, 0, 0);
        }
    }
    #pragma unroll
    for (int j = 0; j < 3; j++) {
        #pragma unroll
        for (int r = 0; r < 4; r++)
            ps[(w*16 + qd*4 + r)*48 + j*16 + l16] = acc[j][r];
    }
    __syncthreads();
    // reduce 8 partials into ps[0..767]
    #pragma unroll
    for (int e = tid; e < 768; e += 512) {
        float v = ps[e];
        #pragma unroll
        for (int p = 1; p < 8; p++) v += ps[p*768 + e];
        ps[e] = v;
    }
    __syncthreads();
    // scatter: e -> (col = e>>4, row = e&15)
    for (int e = tid; e < 768; e += 512) {
        int col = e >> 4, row = e & 15;
        float val = ps[row*48 + col];
        if (col < 16)       dtr_s[row][col] = val;
        else {
            size_t base = ((size_t)(b*L_) + l0 + row)*DS_ + (col & 15);
            if (col < 32) bn[base] = val;
            else          cn[base] = val;
        }
    }
    __syncthreads();
    // dt_proj: thread -> d = tid (exactly DI_ threads); 16 rows; softplus
    {
        int d = tid;
        float wreg[16];
        const float4* wp = (const float4*)(DTW + (size_t)d*16);
        #pragma unroll
        for (int k4 = 0; k4 < 4; k4++) {
            float4 v = wp[k4];
            wreg[4*k4+0] = v.x; wreg[4*k4+1] = v.y;
            wreg[4*k4+2] = v.z; wreg[4*k4+3] = v.w;
        }
        float bias = DTB[d];
        #pragma unroll
        for (int r = 0; r < 16; r++) {
            float a = bias;
            #pragma unroll
            for (int k = 0; k < 16; k++) a = fmaf(dtr_s[r][k], wreg[k], a);
            float dt = a > 20.f ? a : log1pf(__expf(a));
            dtn[((size_t)(b*L_) + l0 + r)*DI_ + d] = dt;
        }
    }
}

// ---------------- chunked selective scan, thread-per-d (no cross-lane) ----------
__global__ __launch_bounds__(128) void scan_phase1(
    const float* __restrict__ dtn, const ushort_t* __restrict__ u_bf,
    const float* __restrict__ bn, const float* __restrict__ Alog,
    float* __restrict__ send, float* __restrict__ aprod)
{
    __shared__ float b_sh[CL_*DS_];
    const int c = blockIdx.x, qy = blockIdx.y, b = blockIdx.z;
    const int tid = threadIdx.x;
    const int d = qy*128 + tid;
    const int l0 = c*CL_;
    for (int f = tid; f < CL_*DS_; f += 128)
        b_sh[f] = bn[((size_t)(b*L_) + l0)*DS_ + f];
    float Ac[DS_], s[DS_], ap[DS_];
    const float* ar = Alog + (size_t)d*DS_;
    #pragma unroll
    for (int n = 0; n < DS_; n++) { Ac[n] = -__expf(ar[n]); s[n] = 0.f; ap[n] = 1.f; }
    __syncthreads();
    const float*    dtp = dtn  + ((size_t)(b*L_ + l0))*DI_ + d;
    const ushort_t* up  = u_bf + ((size_t)(b*L_ + l0))*DI_ + d;
    for (int l = 0; l < CL_; l++) {
        float dt = dtp[(size_t)l*DI_];
        float u  = bf2f(up[(size_t)l*DI_]);
        float dtu = dt*u;
        float bv[DS_];
        #pragma unroll
        for (int n4 = 0; n4 < 4; n4++)
            *(float4*)&bv[4*n4] = *(const float4*)&b_sh[l*DS_ + 4*n4];
        #pragma unroll
        for (int n = 0; n < DS_; n++) {
            float e = __expf(dt*Ac[n]);
            s[n] = fmaf(e, s[n], dtu*bv[n]);
            ap[n] *= e;
        }
    }
    size_t base = (((size_t)c*B_ + b)*DI_ + d)*DS_;
    #pragma unroll
    for (int n4 = 0; n4 < 4; n4++) {
        *(float4*)(send  + base + 4*n4) = *(float4*)&s[4*n4];
        *(float4*)(aprod + base + 4*n4) = *(float4*)&ap[4*n4];
    }
}

__global__ __launch_bounds__(256) void scan_phase2(
    float* __restrict__ send, const float* __restrict__ aprod)
{
    int t = blockIdx.x*256 + threadIdx.x;   // B_*DI_*DS_ = 16384 threads
    float s = 0.f;
    for (int c = 0; c < NC_; c++) {
        size_t idx = (size_t)c*(B_*DI_*DS_) + t;         // coalesced per c
        float tmp = send[idx];
        send[idx] = s;
        s = fmaf(aprod[idx], s, tmp);
    }
}

// Phase 3: re-run chunk with incoming state; fuse (y + u*D)*silu(z) -> bf16.
__global__ __launch_bounds__(128) void scan_phase3(
    const float* __restrict__ dtn, const ushort_t* __restrict__ u_bf,
    const float* __restrict__ bn, const float* __restrict__ cn,
    const float* __restrict__ Alog, const float* __restrict__ Dv,
    const float* __restrict__ sin_, const ushort_t* __restrict__ xz,
    ushort_t* __restrict__ ysb)
{
    __shared__ float b_sh[CL_*DS_];
    __shared__ float c_sh[CL_*DS_];
    const int c = blockIdx.x, qy = blockIdx.y, b = blockIdx.z;
    const int tid = threadIdx.x;
    const int d = qy*128 + tid;
    const int l0 = c*CL_;
    for (int f = tid; f < CL_*DS_; f += 128) {
        size_t src = ((size_t)(b*L_) + l0)*DS_ + f;
        b_sh[f] = bn[src];
        c_sh[f] = cn[src];
    }
    float Ac[DS_], s[DS_];
    const float* ar = Alog + (size_t)d*DS_;
    #pragma unroll
    for (int n = 0; n < DS_; n++) Ac[n] = -__expf(ar[n]);
    {
        size_t base = (((size_t)c*B_ + b)*DI_ + d)*DS_;
        #pragma unroll
        for (int n4 = 0; n4 < 4; n4++)
            *(float4*)&s[4*n4] = *(const float4*)(sin_ + base + 4*n4);
    }
    const float Dd = Dv[d];
    __syncthreads();
    const float*    dtp = dtn  + ((size_t)(b*L_ + l0))*DI_ + d;
    const ushort_t* up  = u_bf + ((size_t)(b*L_ + l0))*DI_ + d;
    const ushort_t* zp  = xz   + ((size_t)(b*L_ + l0))*1024 + 512 + d;
    ushort_t*       yo  = ysb  + ((size_t)(b*L_ + l0))*DI_ + d;
    for (int l = 0; l < CL_; l++) {
        float dt = dtp[(size_t)l*DI_];
        float u  = bf2f(up[(size_t)l*DI_]);
        float z  = bf2f(zp[(size_t)l*1024]);
        float dtu = dt*u;
        float bv[DS_], cv[DS_];
        #pragma unroll
        for (int n4 = 0; n4 < 4; n4++) {
            *(float4*)&bv[4*n4] = *(const float4*)&b_sh[l*DS_ + 4*n4];
            *(float4*)&cv[4*n4] = *(const float4*)&c_sh[l*DS_ + 4*n4];
        }
        float y = u*Dd;
        #pragma unroll
        for (int n = 0; n < DS_; n++) {
            float e = __expf(dt*Ac[n]);
            s[n] = fmaf(e, s[n], dtu*bv[n]);
            y = fmaf(s[n], cv[n], y);
        }
        yo[(size_t)l*DI_] = f2bf(y * siluf(z));
    }
}

// ---------------- final LN + head dot ----------------
__global__ __launch_bounds__(256) void final_kernel(
    const float* __restrict__ h, const float* __restrict__ fw,
    const float* __restrict__ fb, const float* __restrict__ hw,
    const float* __restrict__ hb, float* __restrict__ out)
{
    __shared__ float sm[4];
    int row = blockIdx.x, tid = threadIdx.x;
    float v = h[(size_t)row*DM_ + tid];
    float s = v;
    #pragma unroll
    for (int o = 32; o > 0; o >>= 1) s += __shfl_down(s, o);
    if ((tid & 63) == 0) sm[tid >> 6] = s;
    __syncthreads();
    float mu = (sm[0]+sm[1]+sm[2]+sm[3]) * (1.f/DM_);
    __syncthreads();
    float dv = v - mu;
    float q = dv*dv;
    #pragma unroll
    for (int o = 32; o > 0; o >>= 1) q += __shfl_down(q, o);
    if ((tid & 63) == 0) sm[tid >> 6] = q;
    __syncthreads();
    float var = (sm[0]+sm[1]+sm[2]+sm[3]) * (1.f/DM_);
    float nv = dv * rsqrtf(var + 1e-5f) * fw[tid] + fb[tid];
    float p = nv * hw[tid];
    __syncthreads();
    #pragma unroll
    for (int o = 32; o > 0; o >>= 1) p += __shfl_down(p, o);
    if ((tid & 63) == 0) sm[tid >> 6] = p;
    __syncthreads();
    if (tid == 0) out[row] = sm[0]+sm[1]+sm[2]+sm[3] + hb[0];
}

extern "C" void kernel_launch(void* const* d_in, const int* in_sizes, int n_in,
                              void* d_out, int out_size, void* d_ws, size_t ws_size,
                              hipStream_t stream)
{
    const float* x    = (const float*)d_in[0];
    const float* biw  = (const float*)d_in[1];
    const float* bib  = (const float*)d_in[2];
    const float* ge   = (const float*)d_in[3];
    const float* me   = (const float*)d_in[4];
    const float* lnw  = (const float*)d_in[5];
    const float* lnb  = (const float*)d_in[6];
    const float* ipw  = (const float*)d_in[7];
    const float* cw   = (const float*)d_in[8];
    const float* cb   = (const float*)d_in[9];
    const float* xpw  = (const float*)d_in[10];
    const float* dtw  = (const float*)d_in[11];
    const float* dtb  = (const float*)d_in[12];
    const float* alog = (const float*)d_in[13];
    const float* Dv   = (const float*)d_in[14];
    const float* opw  = (const float*)d_in[15];
    const float* fw   = (const float*)d_in[16];
    const float* fb   = (const float*)d_in[17];
    const float* hw   = (const float*)d_in[18];
    const float* hb   = (const float*)d_in[19];
    float* out = (float*)d_out;

    // workspace layout (float units; 16B-aligned); ~49 MB
    float* ws  = (float*)d_ws;
    float* h     = ws;                                   // 1,048,576 f
    float* scr   = h + (size_t)BLP_*DM_;                 // 655,360 f (hnb)
    float* dtn   = scr + 655360;                         // 2,048,000 f (b,l,d)
    float* bn    = dtn + (size_t)B_*L_*DI_;              // 64,000 f (b,l,n)
    float* cn    = bn + (size_t)B_*L_*DS_;               // 64,000 f
    float* send  = cn + (size_t)B_*L_*DS_;               // 1,638,400 f
    float* aprod = send + (size_t)B_*DI_*DS_*NC_;        // 1,638,400 f
    ushort_t* xz_bf = (ushort_t*)(aprod + (size_t)B_*DI_*DS_*NC_); // BLP_*1024 us
    ushort_t* u_bf  = xz_bf + (size_t)BLP_*1024;         // BLP_*DI_ us
    ushort_t* ysbb  = u_bf + (size_t)BLP_*DI_;           // BLP_*DI_ us
    ushort_t* ipwb  = ysbb + (size_t)BLP_*DI_;           // NL_*1024*DM_ us
    ushort_t* opwb  = ipwb + (size_t)NL_*1024*DM_;       // NL_*DM_*DI_ us
    ushort_t* xpwb  = opwb + (size_t)NL_*DM_*DI_;        // NL_*48*512 us
    ushort_t* hnb   = (ushort_t*)scr;                    // BLP_*DM_ us

    // convert all weights to bf16 in one launch
    const int N0 = NL_*1024*DM_/4, N1 = NL_*DM_*DI_/4, N2 = NL_*48*512/4;
    f2bf3_kernel<<<(N0+N1+N2 + 255)/256, 256, 0, stream>>>(
        ipw, opw, xpw, ipwb, opwb, xpwb, N0, N1, N2);

    embed_kernel<<<BL_, 256, 0, stream>>>(x, biw, bib, ge, me, h);
    for (int i = 0; i < NL_; i++) {
        ln_kernel<<<BL_, 256, 0, stream>>>(h, lnw + i*DM_, lnb + i*DM_, hnb);
        gemm_mfma<false, ushort_t><<<dim3(BLP_/128, 1024/128), 256, 0, stream>>>(
            hnb, ipwb + (size_t)i*1024*DM_, xz_bf, 1024, DM_);
        conv_silu_kernel<<<dim3(32, 8, B_), 256, 0, stream>>>(
            xz_bf, cw + i*DI_*4, cb + i*DI_, u_bf);
        xproj_dt_kernel<<<dim3(125, B_), 512, 0, stream>>>(
            u_bf, xpwb + (size_t)i*48*512, dtw + (size_t)i*DI_*16, dtb + i*DI_,
            bn, cn, dtn);
        scan_phase1<<<dim3(NC_, DI_/128, B_), 128, 0, stream>>>(
            dtn, u_bf, bn, alog + (size_t)i*DI_*DS_, send, aprod);
        scan_phase2<<<B_*DI_*DS_/256, 256, 0, stream>>>(send, aprod);
        scan_phase3<<<dim3(NC_, DI_/128, B_), 128, 0, stream>>>(
            dtn, u_bf, bn, cn, alog + (size_t)i*DI_*DS_, Dv + i*DI_,
            send, xz_bf, ysbb);
        gemm_mfma<true, float><<<dim3(BLP_/128, DM_/128), 256, 0, stream>>>(
            ysbb, opwb + (size_t)i*DM_*DI_, h, DM_, DI_);
    }
    final_kernel<<<BL_, 256, 0, stream>>>(h, fw, fb, hw, hb, out);
}